// Round 6
// baseline (1256.388 us; speedup 1.0000x reference)
//
#include <hip/hip_runtime.h>
#include <hip/hip_bf16.h>
#include <stdint.h>

#define B_  4
#define S_  2048
#define E_  1280
#define H_  5
#define D_  256
#define BH_ 20
#define M_  8192
#define K_  1280

#define SCALE_ 0.027950849718747372f  // 1/sqrt(1280)

typedef __attribute__((ext_vector_type(8))) __bf16 bf16x8;
typedef __attribute__((ext_vector_type(4))) float  f32x4;

__device__ __forceinline__ ushort f2bf(float f) {
  union { float f; uint32_t u; } v; v.f = f;
  return (ushort)((v.u + 0x7FFFu + ((v.u >> 16) & 1u)) >> 16);
}

typedef const __attribute__((address_space(1))) void* gas_cvp;
typedef __attribute__((address_space(3))) void*       las_vp;

__device__ __forceinline__ void glds16(const void* g, void* l) {
  __builtin_amdgcn_global_load_lds((gas_cvp)g, (las_vp)l, 16, 0, 0);
}

// ---------------------------------------------------------------- convert (all 5 tensors, one launch)
__global__ void cvt5_kernel(const float4* __restrict__ s0, const float4* __restrict__ s1,
                            const float4* __restrict__ s2, const float4* __restrict__ s3,
                            const float4* __restrict__ s4,
                            ushort4* __restrict__ d0, ushort4* __restrict__ d1,
                            ushort4* __restrict__ d2, ushort4* __restrict__ d3,
                            ushort4* __restrict__ d4, int nx, int nw) {
  int seg = blockIdx.y;
  const float4* s = (seg == 0) ? s0 : (seg == 1) ? s1 : (seg == 2) ? s2 : (seg == 3) ? s3 : s4;
  ushort4*       d = (seg == 0) ? d0 : (seg == 1) ? d1 : (seg == 2) ? d2 : (seg == 3) ? d3 : d4;
  int n4 = (seg == 0) ? nx : nw;
  int i = blockIdx.x * blockDim.x + threadIdx.x;
  int stride = gridDim.x * blockDim.x;
  for (; i < n4; i += stride) {
    float4 v = s[i];
    ushort4 u;
    u.x = f2bf(v.x); u.y = f2bf(v.y); u.z = f2bf(v.z); u.w = f2bf(v.w);
    d[i] = u;
  }
}

// ---------------------------------------------------------------- fused QKV GEMM
// C[m][n] = sum_k A[m][k] * W[n][k]; blockIdx.y selects {Q(scaled), K, Vt} x n-block
__global__ __launch_bounds__(256, 2)
void gemm_qkv(const ushort* __restrict__ A,
              const ushort* __restrict__ Wq, const ushort* __restrict__ Wk,
              const ushort* __restrict__ Wv,
              ushort* __restrict__ Qo, ushort* __restrict__ Ko, ushort* __restrict__ Vo)
{
  __shared__ __align__(16) ushort Abuf[128 * 64];
  __shared__ __align__(16) ushort Bbuf[128 * 64];
  const int tid  = threadIdx.x;
  const int lane = tid & 63;
  const int wid  = tid >> 6;
  const int m0 = blockIdx.x * 128;
  const int which = blockIdx.y / 10;            // 0=Q 1=K 2=V
  const int n0 = (blockIdx.y % 10) * 128;
  const ushort* W = (which == 0) ? Wq : (which == 1) ? Wk : Wv;
  const int wr = (wid >> 1) * 64;
  const int wc = (wid & 1) * 64;

  f32x4 acc[4][4] = {};
  const int soff = wid * 4096 + lane * 16;

  for (int kk = 0; kk < K_; kk += 64) {
    __syncthreads();
#pragma unroll
    for (int i = 0; i < 4; ++i) {
      int off = soff + i * 1024;
      int row = off >> 7;
      int c8  = (off >> 4) & 7;
      int s8  = c8 ^ (row & 7);
      glds16(A + (size_t)(m0 + row) * K_ + kk + s8 * 8,
             (char*)Abuf + wid * 4096 + i * 1024);
      glds16(W + (size_t)(n0 + row) * K_ + kk + s8 * 8,
             (char*)Bbuf + wid * 4096 + i * 1024);
    }
    __syncthreads();
#pragma unroll
    for (int kt = 0; kt < 2; ++kt) {
      bf16x8 af[4], bfr[4];
#pragma unroll
      for (int mf = 0; mf < 4; ++mf) {
        int row  = wr + mf * 16 + (lane & 15);
        int byte = (row << 7) + kt * 64 + ((lane >> 4) << 4);
        af[mf] = *(const bf16x8*)((const char*)Abuf + (byte ^ ((row & 7) << 4)));
      }
#pragma unroll
      for (int nf = 0; nf < 4; ++nf) {
        int row  = wc + nf * 16 + (lane & 15);
        int byte = (row << 7) + kt * 64 + ((lane >> 4) << 4);
        bfr[nf] = *(const bf16x8*)((const char*)Bbuf + (byte ^ ((row & 7) << 4)));
      }
#pragma unroll
      for (int mf = 0; mf < 4; ++mf)
#pragma unroll
        for (int nf = 0; nf < 4; ++nf)
          acc[mf][nf] = __builtin_amdgcn_mfma_f32_16x16x32_bf16(
              af[mf], bfr[nf], acc[mf][nf], 0, 0, 0);
    }
  }

  // epilogue (block-uniform select)
#pragma unroll
  for (int mf = 0; mf < 4; ++mf) {
#pragma unroll
    for (int nf = 0; nf < 4; ++nf) {
      int mbase = m0 + wr + mf * 16 + ((lane >> 4) << 2);
      int n     = n0 + wc + nf * 16 + (lane & 15);
      int h = n >> 8, dd = n & 255;
      if (which == 0) {       // Q, pre-scaled by 1/sqrt(E)
#pragma unroll
        for (int r = 0; r < 4; ++r) {
          int m = mbase + r;
          Qo[((size_t)(((m >> 11) * H_ + h) * S_ + (m & 2047))) * D_ + dd] =
              f2bf(acc[mf][nf][r] * SCALE_);
        }
      } else if (which == 1) { // K
#pragma unroll
        for (int r = 0; r < 4; ++r) {
          int m = mbase + r;
          Ko[((size_t)(((m >> 11) * H_ + h) * S_ + (m & 2047))) * D_ + dd] =
              f2bf(acc[mf][nf][r]);
        }
      } else {                 // Vt [bh][d][s]
        size_t idx = ((size_t)((mbase >> 11) * H_ + h) * D_ + dd) * S_ + (mbase & 2047);
        ushort4 pk;
        pk.x = f2bf(acc[mf][nf][0]);
        pk.y = f2bf(acc[mf][nf][1]);
        pk.z = f2bf(acc[mf][nf][2]);
        pk.w = f2bf(acc[mf][nf][3]);
        *(ushort4*)(Vo + idx) = pk;
      }
    }
  }
}

// ---------------------------------------------------------------- output-proj GEMM (f32 + bias)
__global__ __launch_bounds__(256, 2)
void gemm_out(const ushort* __restrict__ A, const ushort* __restrict__ W,
              float* __restrict__ OF, const float* __restrict__ bias)
{
  __shared__ __align__(16) ushort Abuf[128 * 64];
  __shared__ __align__(16) ushort Bbuf[128 * 64];
  const int tid  = threadIdx.x;
  const int lane = tid & 63;
  const int wid  = tid >> 6;
  const int m0 = blockIdx.x * 128;
  const int n0 = blockIdx.y * 128;
  const int wr = (wid >> 1) * 64;
  const int wc = (wid & 1) * 64;

  f32x4 acc[4][4] = {};
  const int soff = wid * 4096 + lane * 16;

  for (int kk = 0; kk < K_; kk += 64) {
    __syncthreads();
#pragma unroll
    for (int i = 0; i < 4; ++i) {
      int off = soff + i * 1024;
      int row = off >> 7;
      int c8  = (off >> 4) & 7;
      int s8  = c8 ^ (row & 7);
      glds16(A + (size_t)(m0 + row) * K_ + kk + s8 * 8,
             (char*)Abuf + wid * 4096 + i * 1024);
      glds16(W + (size_t)(n0 + row) * K_ + kk + s8 * 8,
             (char*)Bbuf + wid * 4096 + i * 1024);
    }
    __syncthreads();
#pragma unroll
    for (int kt = 0; kt < 2; ++kt) {
      bf16x8 af[4], bfr[4];
#pragma unroll
      for (int mf = 0; mf < 4; ++mf) {
        int row  = wr + mf * 16 + (lane & 15);
        int byte = (row << 7) + kt * 64 + ((lane >> 4) << 4);
        af[mf] = *(const bf16x8*)((const char*)Abuf + (byte ^ ((row & 7) << 4)));
      }
#pragma unroll
      for (int nf = 0; nf < 4; ++nf) {
        int row  = wc + nf * 16 + (lane & 15);
        int byte = (row << 7) + kt * 64 + ((lane >> 4) << 4);
        bfr[nf] = *(const bf16x8*)((const char*)Bbuf + (byte ^ ((row & 7) << 4)));
      }
#pragma unroll
      for (int mf = 0; mf < 4; ++mf)
#pragma unroll
        for (int nf = 0; nf < 4; ++nf)
          acc[mf][nf] = __builtin_amdgcn_mfma_f32_16x16x32_bf16(
              af[mf], bfr[nf], acc[mf][nf], 0, 0, 0);
    }
  }

#pragma unroll
  for (int mf = 0; mf < 4; ++mf) {
#pragma unroll
    for (int nf = 0; nf < 4; ++nf) {
      int mbase = m0 + wr + mf * 16 + ((lane >> 4) << 2);
      int n     = n0 + wc + nf * 16 + (lane & 15);
      float bv = bias[n];
#pragma unroll
      for (int r = 0; r < 4; ++r)
        OF[(size_t)(mbase + r) * E_ + n] = acc[mf][nf][r] + bv;
    }
  }
}

// ---------------------------------------------------------------- flash attention (swapped QK^T)
// K: LDS double-buffered (swizzled, stage-ahead). V: NOT staged — read from
// global (L2-resident per-XCD after head-clustering); removes the 8-way-conflict
// V reads and shrinks LDS to 37 KB -> 4 blocks/CU.
// Q(prescaled),K: [bh][s][d] bf16; Vt: [bh][d][s] bf16; AO: [b][s][e] bf16
__global__ __launch_bounds__(256, 4)
void flash_attn_kernel(const ushort* __restrict__ Q, const ushort* __restrict__ Kg,
                       const ushort* __restrict__ Vt, ushort* __restrict__ AO)
{
  __shared__ __align__(16) ushort Kbuf[2][32 * 256];   // 2 x 16 KB, swizzled
  __shared__ __align__(16) char   Pbuf[4 * 16 * 80];   // per-wave P (16 x 32 bf16, pitch 80)

  const int lane = threadIdx.x & 63;
  const int wid  = threadIdx.x >> 6;
  const int l15  = lane & 15;
  const int l4   = lane >> 4;          // 0..3

  // XCD-clustered remap (640 % 8 == 0, bijective); big causal tiles first.
  const int id  = blockIdx.x;
  const int idp = (id & 7) * 80 + (id >> 3);
  const int bh  = idp >> 5;                    // 0..19
  const int tq  = 31 - (idp & 31);             // 0..31
  const int q0w = tq * 64 + wid * 16;          // this wave's 16 q-rows

  const ushort* Qb = Q  + (size_t)bh * S_ * D_;
  const ushort* Kb = Kg + (size_t)bh * S_ * D_;
  const ushort* Vb = Vt + (size_t)bh * D_ * S_;

  // Q fragments (B-operand): lane holds q=q0w+l15, d = kt*32 + l4*8 + j
  bf16x8 bq[8];
  {
    const ushort* qrow = Qb + (size_t)(q0w + l15) * D_ + l4 * 8;
#pragma unroll
    for (int kt = 0; kt < 8; ++kt) bq[kt] = *(const bf16x8*)(qrow + kt * 32);
  }

  f32x4 o[16] = {};
  float m_s = -1e30f, l_s = 0.f;       // stats for q = q0w + l15 (per-lane)

  char* Pw = Pbuf + wid * 1280;
  const int nt = 2 * tq + 2;

  // stage K [32][256] (swizzled source), 4 x glds16 per thread
#define STAGE_K(bufi, kvbase)                                                 \
  do {                                                                        \
    _Pragma("unroll")                                                         \
    for (int i_ = 0; i_ < 4; ++i_) {                                          \
      int off_ = wid * 4096 + i_ * 1024 + lane * 16;                          \
      int rK_  = off_ >> 9;                                                   \
      int s8_  = ((off_ >> 4) & 31) ^ (rK_ & 7);                              \
      glds16(Kb + (size_t)((kvbase) + rK_) * D_ + s8_ * 8,                    \
             (char*)Kbuf[bufi] + wid * 4096 + i_ * 1024);                     \
    }                                                                         \
  } while (0)

  STAGE_K(0, 0);
  __syncthreads();

  int cur = 0;
  for (int t = 0; t < nt; ++t) {
    const int kv0 = t * 32;
    if (t + 1 < nt) STAGE_K(cur ^ 1, kv0 + 32);   // issue-ahead (no wait)

    if (kv0 <= q0w + 15) {   // wave-uniform: skip fully-masked tiles
      // ---- S^T = K Q^T : sacc[h2] holds kv = kv0 + h2*16 + l4*4 + r, q = q0w + l15
      f32x4 sacc[2] = {};
      const char* kb = (const char*)Kbuf[cur];
      __builtin_amdgcn_s_setprio(1);
#pragma unroll
      for (int kt = 0; kt < 8; ++kt) {
#pragma unroll
        for (int h2 = 0; h2 < 2; ++h2) {
          int row  = h2 * 16 + l15;                       // kv-local row
          int byte = (row << 9) + kt * 64 + (l4 << 4);
          bf16x8 kf = *(const bf16x8*)(kb + (byte ^ ((row & 7) << 4)));
          sacc[h2] = __builtin_amdgcn_mfma_f32_16x16x32_bf16(kf, bq[kt], sacc[h2], 0, 0, 0);
        }
      }
      __builtin_amdgcn_s_setprio(0);

      // ---- online softmax (per-lane scalar stats for q = q0w + l15)
      const bool msk = (kv0 + 31 > q0w);
      float sv[2][4];
#pragma unroll
      for (int h2 = 0; h2 < 2; ++h2)
#pragma unroll
        for (int r = 0; r < 4; ++r) {
          float s = sacc[h2][r];                          // Q pre-scaled
          if (msk && (kv0 + h2 * 16 + l4 * 4 + r > q0w + l15)) s = -1e30f;
          sv[h2][r] = s;
        }
      float pm = sv[0][0];
#pragma unroll
      for (int h2 = 0; h2 < 2; ++h2)
#pragma unroll
        for (int r = 0; r < 4; ++r) pm = fmaxf(pm, sv[h2][r]);
      pm = fmaxf(pm, __shfl_xor(pm, 16, 64));
      pm = fmaxf(pm, __shfl_xor(pm, 32, 64));

      if (__any(pm > m_s + 8.f)) {     // rescale path
        float mn = fmaxf(m_s, pm);
        float alpha = __expf(m_s - mn);
        m_s = mn;
#pragma unroll
        for (int h2 = 0; h2 < 2; ++h2)
#pragma unroll
          for (int r = 0; r < 4; ++r) sv[h2][r] = __expf(sv[h2][r] - m_s);
        float rs = 0.f;
#pragma unroll
        for (int h2 = 0; h2 < 2; ++h2)
#pragma unroll
          for (int r = 0; r < 4; ++r) rs += sv[h2][r];
        rs += __shfl_xor(rs, 16, 64);
        rs += __shfl_xor(rs, 32, 64);
        l_s = l_s * alpha + rs;
        // redistribute alpha from q=l15 lanes to q=l4*4+r accumulator rows
        float al[4];
#pragma unroll
        for (int r = 0; r < 4; ++r)
          al[r] = __shfl(alpha, (lane & 48) + ((lane & 48) >> 2) + r, 64);
#pragma unroll
        for (int nf = 0; nf < 16; ++nf)
#pragma unroll
          for (int r = 0; r < 4; ++r) o[nf][r] *= al[r];
      } else {                         // defer-max (T13): no rescale
#pragma unroll
        for (int h2 = 0; h2 < 2; ++h2)
#pragma unroll
          for (int r = 0; r < 4; ++r) sv[h2][r] = __expf(sv[h2][r] - m_s);
        float rs = 0.f;
#pragma unroll
        for (int h2 = 0; h2 < 2; ++h2)
#pragma unroll
          for (int r = 0; r < 4; ++r) rs += sv[h2][r];
        rs += __shfl_xor(rs, 16, 64);
        rs += __shfl_xor(rs, 32, 64);
        l_s += rs;
      }

      // ---- P to wave-private LDS: row q=l15, cols kv = h2*16 + l4*4 + {0..3}
      ushort4 w0, w1;
      w0.x = f2bf(sv[0][0]); w0.y = f2bf(sv[0][1]); w0.z = f2bf(sv[0][2]); w0.w = f2bf(sv[0][3]);
      w1.x = f2bf(sv[1][0]); w1.y = f2bf(sv[1][1]); w1.z = f2bf(sv[1][2]); w1.w = f2bf(sv[1][3]);
      *(ushort4*)(Pw + l15 * 80 + l4 * 8)      = w0;
      *(ushort4*)(Pw + l15 * 80 + 32 + l4 * 8) = w1;
      bf16x8 pa = *(const bf16x8*)(Pw + l15 * 80 + l4 * 16);  // A-frag: row l15, k=l4*8..+7

      // ---- O += P V  (C[q][d]: q = l4*4+r, d = nf*16+l15); V direct from global
      const ushort* Vtt = Vb + (size_t)l15 * S_ + kv0 + l4 * 8;
      __builtin_amdgcn_s_setprio(1);
#pragma unroll
      for (int nf = 0; nf < 16; ++nf) {
        bf16x8 bv = *(const bf16x8*)(Vtt + (size_t)(nf * 16) * S_);
        o[nf] = __builtin_amdgcn_mfma_f32_16x16x32_bf16(pa, bv, o[nf], 0, 0, 0);
      }
      __builtin_amdgcn_s_setprio(0);
    }

    __syncthreads();   // single per-iter drain (K stage + LDS reads)
    cur ^= 1;
  }
#undef STAGE_K

  // ---- epilogue: redistribute 1/l (q=l15 -> q=l4*4+r), write bf16
  float linv = 1.0f / l_s;
  float inv[4];
#pragma unroll
  for (int r = 0; r < 4; ++r)
    inv[r] = __shfl(linv, (lane & 48) + ((lane & 48) >> 2) + r, 64);
  int b = bh / H_, h = bh % H_;
  const int dd0 = h * D_;
#pragma unroll
  for (int nf = 0; nf < 16; ++nf) {
    int dd = dd0 + nf * 16 + l15;
#pragma unroll
    for (int r = 0; r < 4; ++r) {
      int s = q0w + l4 * 4 + r;
      AO[(size_t)(b * S_ + s) * E_ + dd] = f2bf(o[nf][r] * inv[r]);
    }
  }
}

// ---------------------------------------------------------------- launch
extern "C" void kernel_launch(void* const* d_in, const int* in_sizes, int n_in,
                              void* d_out, int out_size, void* d_ws, size_t ws_size,
                              hipStream_t stream) {
  const float* x  = (const float*)d_in[0];
  const float* Wq = (const float*)d_in[1];
  const float* Wk = (const float*)d_in[2];
  const float* Wv = (const float*)d_in[3];
  const float* Wu = (const float*)d_in[4];
  const float* bu = (const float*)d_in[5];

  char* ws = (char*)d_ws;
  ushort* xbf = (ushort*)(ws + 0);          // 8192x1280 bf16
  ushort* Wqb = (ushort*)(ws + 20971520);
  ushort* Wkb = (ushort*)(ws + 24248320);
  ushort* Wvb = (ushort*)(ws + 27525120);
  ushort* Wub = (ushort*)(ws + 30801920);
  ushort* Qw  = (ushort*)(ws + 34078720);   // [20][2048][256] (pre-scaled)
  ushort* Kw  = (ushort*)(ws + 55050240);   // [20][2048][256]
  ushort* Vtw = (ushort*)(ws + 76021760);   // [20][256][2048]
  ushort* AOw = (ushort*)(ws + 96993280);   // [4][2048][1280]

  cvt5_kernel<<<dim3(1024, 5), 256, 0, stream>>>(
      (const float4*)x, (const float4*)Wq, (const float4*)Wk,
      (const float4*)Wv, (const float4*)Wu,
      (ushort4*)xbf, (ushort4*)Wqb, (ushort4*)Wkb, (ushort4*)Wvb, (ushort4*)Wub,
      M_ * K_ / 4, E_ * E_ / 4);

  gemm_qkv<<<dim3(M_ / 128, 30), 256, 0, stream>>>(xbf, Wqb, Wkb, Wvb, Qw, Kw, Vtw);

  flash_attn_kernel<<<640, 256, 0, stream>>>(Qw, Kw, Vtw, AOw);

  gemm_out<<<dim3(M_ / 128, E_ / 128), 256, 0, stream>>>(AOw, Wub, (float*)d_out, bu);
}

// Round 7
// 542.757 us; speedup vs baseline: 2.3148x; 2.3148x over previous
//
#include <hip/hip_runtime.h>
#include <hip/hip_bf16.h>
#include <stdint.h>

#define B_  4
#define S_  2048
#define E_  1280
#define H_  5
#define D_  256
#define BH_ 20
#define M_  8192
#define K_  1280

#define SCALE_ 0.027950849718747372f  // 1/sqrt(1280)

typedef __attribute__((ext_vector_type(8))) __bf16 bf16x8;
typedef __attribute__((ext_vector_type(4))) float  f32x4;

__device__ __forceinline__ ushort f2bf(float f) {
  union { float f; uint32_t u; } v; v.f = f;
  return (ushort)((v.u + 0x7FFFu + ((v.u >> 16) & 1u)) >> 16);
}

typedef const __attribute__((address_space(1))) void* gas_cvp;
typedef __attribute__((address_space(3))) void*       las_vp;

__device__ __forceinline__ void glds16(const void* g, void* l) {
  __builtin_amdgcn_global_load_lds((gas_cvp)g, (las_vp)l, 16, 0, 0);
}

// ---------------------------------------------------------------- convert (all 5 tensors, one launch)
__global__ void cvt5_kernel(const float4* __restrict__ s0, const float4* __restrict__ s1,
                            const float4* __restrict__ s2, const float4* __restrict__ s3,
                            const float4* __restrict__ s4,
                            ushort4* __restrict__ d0, ushort4* __restrict__ d1,
                            ushort4* __restrict__ d2, ushort4* __restrict__ d3,
                            ushort4* __restrict__ d4, int nx, int nw) {
  int seg = blockIdx.y;
  const float4* s = (seg == 0) ? s0 : (seg == 1) ? s1 : (seg == 2) ? s2 : (seg == 3) ? s3 : s4;
  ushort4*       d = (seg == 0) ? d0 : (seg == 1) ? d1 : (seg == 2) ? d2 : (seg == 3) ? d3 : d4;
  int n4 = (seg == 0) ? nx : nw;
  int i = blockIdx.x * blockDim.x + threadIdx.x;
  int stride = gridDim.x * blockDim.x;
  for (; i < n4; i += stride) {
    float4 v = s[i];
    ushort4 u;
    u.x = f2bf(v.x); u.y = f2bf(v.y); u.z = f2bf(v.z); u.w = f2bf(v.w);
    d[i] = u;
  }
}

// ---------------------------------------------------------------- fused QKV GEMM
// C[m][n] = sum_k A[m][k] * W[n][k]; blockIdx.y selects {Q(scaled), K, Vt} x n-block
__global__ __launch_bounds__(256, 2)
void gemm_qkv(const ushort* __restrict__ A,
              const ushort* __restrict__ Wq, const ushort* __restrict__ Wk,
              const ushort* __restrict__ Wv,
              ushort* __restrict__ Qo, ushort* __restrict__ Ko, ushort* __restrict__ Vo)
{
  __shared__ __align__(16) ushort Abuf[128 * 64];
  __shared__ __align__(16) ushort Bbuf[128 * 64];
  const int tid  = threadIdx.x;
  const int lane = tid & 63;
  const int wid  = tid >> 6;
  const int m0 = blockIdx.x * 128;
  const int which = blockIdx.y / 10;            // 0=Q 1=K 2=V
  const int n0 = (blockIdx.y % 10) * 128;
  const ushort* W = (which == 0) ? Wq : (which == 1) ? Wk : Wv;
  const int wr = (wid >> 1) * 64;
  const int wc = (wid & 1) * 64;

  f32x4 acc[4][4] = {};
  const int soff = wid * 4096 + lane * 16;

  for (int kk = 0; kk < K_; kk += 64) {
    __syncthreads();
#pragma unroll
    for (int i = 0; i < 4; ++i) {
      int off = soff + i * 1024;
      int row = off >> 7;
      int c8  = (off >> 4) & 7;
      int s8  = c8 ^ (row & 7);
      glds16(A + (size_t)(m0 + row) * K_ + kk + s8 * 8,
             (char*)Abuf + wid * 4096 + i * 1024);
      glds16(W + (size_t)(n0 + row) * K_ + kk + s8 * 8,
             (char*)Bbuf + wid * 4096 + i * 1024);
    }
    __syncthreads();
#pragma unroll
    for (int kt = 0; kt < 2; ++kt) {
      bf16x8 af[4], bfr[4];
#pragma unroll
      for (int mf = 0; mf < 4; ++mf) {
        int row  = wr + mf * 16 + (lane & 15);
        int byte = (row << 7) + kt * 64 + ((lane >> 4) << 4);
        af[mf] = *(const bf16x8*)((const char*)Abuf + (byte ^ ((row & 7) << 4)));
      }
#pragma unroll
      for (int nf = 0; nf < 4; ++nf) {
        int row  = wc + nf * 16 + (lane & 15);
        int byte = (row << 7) + kt * 64 + ((lane >> 4) << 4);
        bfr[nf] = *(const bf16x8*)((const char*)Bbuf + (byte ^ ((row & 7) << 4)));
      }
#pragma unroll
      for (int mf = 0; mf < 4; ++mf)
#pragma unroll
        for (int nf = 0; nf < 4; ++nf)
          acc[mf][nf] = __builtin_amdgcn_mfma_f32_16x16x32_bf16(
              af[mf], bfr[nf], acc[mf][nf], 0, 0, 0);
    }
  }

  // epilogue (block-uniform select)
#pragma unroll
  for (int mf = 0; mf < 4; ++mf) {
#pragma unroll
    for (int nf = 0; nf < 4; ++nf) {
      int mbase = m0 + wr + mf * 16 + ((lane >> 4) << 2);
      int n     = n0 + wc + nf * 16 + (lane & 15);
      int h = n >> 8, dd = n & 255;
      if (which == 0) {       // Q, pre-scaled by 1/sqrt(E)
#pragma unroll
        for (int r = 0; r < 4; ++r) {
          int m = mbase + r;
          Qo[((size_t)(((m >> 11) * H_ + h) * S_ + (m & 2047))) * D_ + dd] =
              f2bf(acc[mf][nf][r] * SCALE_);
        }
      } else if (which == 1) { // K
#pragma unroll
        for (int r = 0; r < 4; ++r) {
          int m = mbase + r;
          Ko[((size_t)(((m >> 11) * H_ + h) * S_ + (m & 2047))) * D_ + dd] =
              f2bf(acc[mf][nf][r]);
        }
      } else {                 // Vt [bh][d][s]
        size_t idx = ((size_t)((mbase >> 11) * H_ + h) * D_ + dd) * S_ + (mbase & 2047);
        ushort4 pk;
        pk.x = f2bf(acc[mf][nf][0]);
        pk.y = f2bf(acc[mf][nf][1]);
        pk.z = f2bf(acc[mf][nf][2]);
        pk.w = f2bf(acc[mf][nf][3]);
        *(ushort4*)(Vo + idx) = pk;
      }
    }
  }
}

// ---------------------------------------------------------------- output-proj GEMM (f32 + bias)
__global__ __launch_bounds__(256, 2)
void gemm_out(const ushort* __restrict__ A, const ushort* __restrict__ W,
              float* __restrict__ OF, const float* __restrict__ bias)
{
  __shared__ __align__(16) ushort Abuf[128 * 64];
  __shared__ __align__(16) ushort Bbuf[128 * 64];
  const int tid  = threadIdx.x;
  const int lane = tid & 63;
  const int wid  = tid >> 6;
  const int m0 = blockIdx.x * 128;
  const int n0 = blockIdx.y * 128;
  const int wr = (wid >> 1) * 64;
  const int wc = (wid & 1) * 64;

  f32x4 acc[4][4] = {};
  const int soff = wid * 4096 + lane * 16;

  for (int kk = 0; kk < K_; kk += 64) {
    __syncthreads();
#pragma unroll
    for (int i = 0; i < 4; ++i) {
      int off = soff + i * 1024;
      int row = off >> 7;
      int c8  = (off >> 4) & 7;
      int s8  = c8 ^ (row & 7);
      glds16(A + (size_t)(m0 + row) * K_ + kk + s8 * 8,
             (char*)Abuf + wid * 4096 + i * 1024);
      glds16(W + (size_t)(n0 + row) * K_ + kk + s8 * 8,
             (char*)Bbuf + wid * 4096 + i * 1024);
    }
    __syncthreads();
#pragma unroll
    for (int kt = 0; kt < 2; ++kt) {
      bf16x8 af[4], bfr[4];
#pragma unroll
      for (int mf = 0; mf < 4; ++mf) {
        int row  = wr + mf * 16 + (lane & 15);
        int byte = (row << 7) + kt * 64 + ((lane >> 4) << 4);
        af[mf] = *(const bf16x8*)((const char*)Abuf + (byte ^ ((row & 7) << 4)));
      }
#pragma unroll
      for (int nf = 0; nf < 4; ++nf) {
        int row  = wc + nf * 16 + (lane & 15);
        int byte = (row << 7) + kt * 64 + ((lane >> 4) << 4);
        bfr[nf] = *(const bf16x8*)((const char*)Bbuf + (byte ^ ((row & 7) << 4)));
      }
#pragma unroll
      for (int mf = 0; mf < 4; ++mf)
#pragma unroll
        for (int nf = 0; nf < 4; ++nf)
          acc[mf][nf] = __builtin_amdgcn_mfma_f32_16x16x32_bf16(
              af[mf], bfr[nf], acc[mf][nf], 0, 0, 0);
    }
  }

#pragma unroll
  for (int mf = 0; mf < 4; ++mf) {
#pragma unroll
    for (int nf = 0; nf < 4; ++nf) {
      int mbase = m0 + wr + mf * 16 + ((lane >> 4) << 2);
      int n     = n0 + wc + nf * 16 + (lane & 15);
      float bv = bias[n];
#pragma unroll
      for (int r = 0; r < 4; ++r)
        OF[(size_t)(mbase + r) * E_ + n] = acc[mf][nf][r] + bv;
    }
  }
}

// ---------------------------------------------------------------- flash attention (swapped QK^T)
// K: LDS double-buffered (swizzled, stage-ahead). V: NOT staged — read from
// global (L2-resident per-XCD after head-clustering). LDS 37 KB.
// launch_bounds (256,2): R6's (256,4) capped regs at 128 -> spilled the
// 64-reg O accumulator to scratch (WRITE_SIZE 990 MB). Never trade regs for occupancy here.
// Q(prescaled),K: [bh][s][d] bf16; Vt: [bh][d][s] bf16; AO: [b][s][e] bf16
__global__ __launch_bounds__(256, 2)
void flash_attn_kernel(const ushort* __restrict__ Q, const ushort* __restrict__ Kg,
                       const ushort* __restrict__ Vt, ushort* __restrict__ AO)
{
  __shared__ __align__(16) ushort Kbuf[2][32 * 256];   // 2 x 16 KB, swizzled
  __shared__ __align__(16) char   Pbuf[4 * 16 * 80];   // per-wave P (16 x 32 bf16, pitch 80)

  const int lane = threadIdx.x & 63;
  const int wid  = threadIdx.x >> 6;
  const int l15  = lane & 15;
  const int l4   = lane >> 4;          // 0..3

  // XCD-clustered remap (640 % 8 == 0, bijective); big causal tiles first.
  const int id  = blockIdx.x;
  const int idp = (id & 7) * 80 + (id >> 3);
  const int bh  = idp >> 5;                    // 0..19
  const int tq  = 31 - (idp & 31);             // 0..31
  const int q0w = tq * 64 + wid * 16;          // this wave's 16 q-rows

  const ushort* Qb = Q  + (size_t)bh * S_ * D_;
  const ushort* Kb = Kg + (size_t)bh * S_ * D_;
  const ushort* Vb = Vt + (size_t)bh * D_ * S_;

  // Q fragments (B-operand): lane holds q=q0w+l15, d = kt*32 + l4*8 + j
  bf16x8 bq[8];
  {
    const ushort* qrow = Qb + (size_t)(q0w + l15) * D_ + l4 * 8;
#pragma unroll
    for (int kt = 0; kt < 8; ++kt) bq[kt] = *(const bf16x8*)(qrow + kt * 32);
  }

  f32x4 o[16] = {};
  float m_s = -1e30f, l_s = 0.f;       // stats for q = q0w + l15 (per-lane)

  char* Pw = Pbuf + wid * 1280;
  const int nt = 2 * tq + 2;

  // stage K [32][256] (swizzled source), 4 x glds16 per thread
#define STAGE_K(bufi, kvbase)                                                 \
  do {                                                                        \
    _Pragma("unroll")                                                         \
    for (int i_ = 0; i_ < 4; ++i_) {                                          \
      int off_ = wid * 4096 + i_ * 1024 + lane * 16;                          \
      int rK_  = off_ >> 9;                                                   \
      int s8_  = ((off_ >> 4) & 31) ^ (rK_ & 7);                              \
      glds16(Kb + (size_t)((kvbase) + rK_) * D_ + s8_ * 8,                    \
             (char*)Kbuf[bufi] + wid * 4096 + i_ * 1024);                     \
    }                                                                         \
  } while (0)

  STAGE_K(0, 0);
  __syncthreads();

  int cur = 0;
  for (int t = 0; t < nt; ++t) {
    const int kv0 = t * 32;
    if (t + 1 < nt) STAGE_K(cur ^ 1, kv0 + 32);   // issue-ahead (no wait)

    if (kv0 <= q0w + 15) {   // wave-uniform: skip fully-masked tiles
      // ---- S^T = K Q^T : sacc[h2] holds kv = kv0 + h2*16 + l4*4 + r, q = q0w + l15
      f32x4 sacc[2] = {};
      const char* kb = (const char*)Kbuf[cur];
      __builtin_amdgcn_s_setprio(1);
#pragma unroll
      for (int kt = 0; kt < 8; ++kt) {
#pragma unroll
        for (int h2 = 0; h2 < 2; ++h2) {
          int row  = h2 * 16 + l15;                       // kv-local row
          int byte = (row << 9) + kt * 64 + (l4 << 4);
          bf16x8 kf = *(const bf16x8*)(kb + (byte ^ ((row & 7) << 4)));
          sacc[h2] = __builtin_amdgcn_mfma_f32_16x16x32_bf16(kf, bq[kt], sacc[h2], 0, 0, 0);
        }
      }
      __builtin_amdgcn_s_setprio(0);

      // ---- online softmax (per-lane scalar stats for q = q0w + l15)
      const bool msk = (kv0 + 31 > q0w);
      float sv[2][4];
#pragma unroll
      for (int h2 = 0; h2 < 2; ++h2)
#pragma unroll
        for (int r = 0; r < 4; ++r) {
          float s = sacc[h2][r];                          // Q pre-scaled
          if (msk && (kv0 + h2 * 16 + l4 * 4 + r > q0w + l15)) s = -1e30f;
          sv[h2][r] = s;
        }
      float pm = sv[0][0];
#pragma unroll
      for (int h2 = 0; h2 < 2; ++h2)
#pragma unroll
        for (int r = 0; r < 4; ++r) pm = fmaxf(pm, sv[h2][r]);
      pm = fmaxf(pm, __shfl_xor(pm, 16, 64));
      pm = fmaxf(pm, __shfl_xor(pm, 32, 64));

      if (__any(pm > m_s + 8.f)) {     // rescale path
        float mn = fmaxf(m_s, pm);
        float alpha = __expf(m_s - mn);
        m_s = mn;
#pragma unroll
        for (int h2 = 0; h2 < 2; ++h2)
#pragma unroll
          for (int r = 0; r < 4; ++r) sv[h2][r] = __expf(sv[h2][r] - m_s);
        float rs = 0.f;
#pragma unroll
        for (int h2 = 0; h2 < 2; ++h2)
#pragma unroll
          for (int r = 0; r < 4; ++r) rs += sv[h2][r];
        rs += __shfl_xor(rs, 16, 64);
        rs += __shfl_xor(rs, 32, 64);
        l_s = l_s * alpha + rs;
        // redistribute alpha from q=l15 lanes to q=l4*4+r accumulator rows
        float al[4];
#pragma unroll
        for (int r = 0; r < 4; ++r)
          al[r] = __shfl(alpha, (lane & 48) + ((lane & 48) >> 2) + r, 64);
#pragma unroll
        for (int nf = 0; nf < 16; ++nf)
#pragma unroll
          for (int r = 0; r < 4; ++r) o[nf][r] *= al[r];
      } else {                         // defer-max (T13): no rescale
#pragma unroll
        for (int h2 = 0; h2 < 2; ++h2)
#pragma unroll
          for (int r = 0; r < 4; ++r) sv[h2][r] = __expf(sv[h2][r] - m_s);
        float rs = 0.f;
#pragma unroll
        for (int h2 = 0; h2 < 2; ++h2)
#pragma unroll
          for (int r = 0; r < 4; ++r) rs += sv[h2][r];
        rs += __shfl_xor(rs, 16, 64);
        rs += __shfl_xor(rs, 32, 64);
        l_s += rs;
      }

      // ---- P to wave-private LDS: row q=l15, cols kv = h2*16 + l4*4 + {0..3}
      ushort4 w0, w1;
      w0.x = f2bf(sv[0][0]); w0.y = f2bf(sv[0][1]); w0.z = f2bf(sv[0][2]); w0.w = f2bf(sv[0][3]);
      w1.x = f2bf(sv[1][0]); w1.y = f2bf(sv[1][1]); w1.z = f2bf(sv[1][2]); w1.w = f2bf(sv[1][3]);
      *(ushort4*)(Pw + l15 * 80 + l4 * 8)      = w0;
      *(ushort4*)(Pw + l15 * 80 + 32 + l4 * 8) = w1;
      bf16x8 pa = *(const bf16x8*)(Pw + l15 * 80 + l4 * 16);  // A-frag: row l15, k=l4*8..+7

      // ---- O += P V  (C[q][d]: q = l4*4+r, d = nf*16+l15); V direct from global
      const ushort* Vtt = Vb + (size_t)l15 * S_ + kv0 + l4 * 8;
      __builtin_amdgcn_s_setprio(1);
#pragma unroll
      for (int nf = 0; nf < 16; ++nf) {
        bf16x8 bv = *(const bf16x8*)(Vtt + (size_t)(nf * 16) * S_);
        o[nf] = __builtin_amdgcn_mfma_f32_16x16x32_bf16(pa, bv, o[nf], 0, 0, 0);
      }
      __builtin_amdgcn_s_setprio(0);
    }

    __syncthreads();   // single per-iter drain (K stage + LDS reads)
    cur ^= 1;
  }
#undef STAGE_K

  // ---- epilogue: redistribute 1/l (q=l15 -> q=l4*4+r), write bf16
  float linv = 1.0f / l_s;
  float inv[4];
#pragma unroll
  for (int r = 0; r < 4; ++r)
    inv[r] = __shfl(linv, (lane & 48) + ((lane & 48) >> 2) + r, 64);
  int b = bh / H_, h = bh % H_;
  const int dd0 = h * D_;
#pragma unroll
  for (int nf = 0; nf < 16; ++nf) {
    int dd = dd0 + nf * 16 + l15;
#pragma unroll
    for (int r = 0; r < 4; ++r) {
      int s = q0w + l4 * 4 + r;
      AO[(size_t)(b * S_ + s) * E_ + dd] = f2bf(o[nf][r] * inv[r]);
    }
  }
}

// ---------------------------------------------------------------- launch
extern "C" void kernel_launch(void* const* d_in, const int* in_sizes, int n_in,
                              void* d_out, int out_size, void* d_ws, size_t ws_size,
                              hipStream_t stream) {
  const float* x  = (const float*)d_in[0];
  const float* Wq = (const float*)d_in[1];
  const float* Wk = (const float*)d_in[2];
  const float* Wv = (const float*)d_in[3];
  const float* Wu = (const float*)d_in[4];
  const float* bu = (const float*)d_in[5];

  char* ws = (char*)d_ws;
  ushort* xbf = (ushort*)(ws + 0);          // 8192x1280 bf16
  ushort* Wqb = (ushort*)(ws + 20971520);
  ushort* Wkb = (ushort*)(ws + 24248320);
  ushort* Wvb = (ushort*)(ws + 27525120);
  ushort* Wub = (ushort*)(ws + 30801920);
  ushort* Qw  = (ushort*)(ws + 34078720);   // [20][2048][256] (pre-scaled)
  ushort* Kw  = (ushort*)(ws + 55050240);   // [20][2048][256]
  ushort* Vtw = (ushort*)(ws + 76021760);   // [20][256][2048]
  ushort* AOw = (ushort*)(ws + 96993280);   // [4][2048][1280]

  cvt5_kernel<<<dim3(1024, 5), 256, 0, stream>>>(
      (const float4*)x, (const float4*)Wq, (const float4*)Wk,
      (const float4*)Wv, (const float4*)Wu,
      (ushort4*)xbf, (ushort4*)Wqb, (ushort4*)Wkb, (ushort4*)Wvb, (ushort4*)Wub,
      M_ * K_ / 4, E_ * E_ / 4);

  gemm_qkv<<<dim3(M_ / 128, 30), 256, 0, stream>>>(xbf, Wqb, Wkb, Wvb, Qw, Kw, Vtw);

  flash_attn_kernel<<<640, 256, 0, stream>>>(Qw, Kw, Vtw, AOw);

  gemm_out<<<dim3(M_ / 128, E_ / 128), 256, 0, stream>>>(AOw, Wub, (float*)d_out, bu);
}

// Round 8
// 356.856 us; speedup vs baseline: 3.5207x; 1.5209x over previous
//
#include <hip/hip_runtime.h>
#include <hip/hip_bf16.h>
#include <stdint.h>

#define B_  4
#define S_  2048
#define E_  1280
#define H_  5
#define D_  256
#define BH_ 20
#define M_  8192
#define K_  1280

#define SCALE_ 0.027950849718747372f  // 1/sqrt(1280)

typedef __attribute__((ext_vector_type(8))) __bf16 bf16x8;
typedef __attribute__((ext_vector_type(4))) float  f32x4;

__device__ __forceinline__ ushort f2bf(float f) {
  union { float f; uint32_t u; } v; v.f = f;
  return (ushort)((v.u + 0x7FFFu + ((v.u >> 16) & 1u)) >> 16);
}

typedef const __attribute__((address_space(1))) void* gas_cvp;
typedef __attribute__((address_space(3))) void*       las_vp;

__device__ __forceinline__ void glds16(const void* g, void* l) {
  __builtin_amdgcn_global_load_lds((gas_cvp)g, (las_vp)l, 16, 0, 0);
}

// ---------------------------------------------------------------- convert (all 5 tensors, one launch)
__global__ void cvt5_kernel(const float4* __restrict__ s0, const float4* __restrict__ s1,
                            const float4* __restrict__ s2, const float4* __restrict__ s3,
                            const float4* __restrict__ s4,
                            ushort4* __restrict__ d0, ushort4* __restrict__ d1,
                            ushort4* __restrict__ d2, ushort4* __restrict__ d3,
                            ushort4* __restrict__ d4, int nx, int nw) {
  int seg = blockIdx.y;
  const float4* s = (seg == 0) ? s0 : (seg == 1) ? s1 : (seg == 2) ? s2 : (seg == 3) ? s3 : s4;
  ushort4*       d = (seg == 0) ? d0 : (seg == 1) ? d1 : (seg == 2) ? d2 : (seg == 3) ? d3 : d4;
  int n4 = (seg == 0) ? nx : nw;
  int i = blockIdx.x * blockDim.x + threadIdx.x;
  int stride = gridDim.x * blockDim.x;
  for (; i < n4; i += stride) {
    float4 v = s[i];
    ushort4 u;
    u.x = f2bf(v.x); u.y = f2bf(v.y); u.z = f2bf(v.z); u.w = f2bf(v.w);
    d[i] = u;
  }
}

// ---------------------------------------------------------------- fused QKV GEMM
// C[m][n] = sum_k A[m][k] * W[n][k]; blockIdx.y selects {Q(scaled), K, Vt} x n-block
__global__ __launch_bounds__(256, 2)
void gemm_qkv(const ushort* __restrict__ A,
              const ushort* __restrict__ Wq, const ushort* __restrict__ Wk,
              const ushort* __restrict__ Wv,
              ushort* __restrict__ Qo, ushort* __restrict__ Ko, ushort* __restrict__ Vo)
{
  __shared__ __align__(16) ushort Abuf[128 * 64];
  __shared__ __align__(16) ushort Bbuf[128 * 64];
  const int tid  = threadIdx.x;
  const int lane = tid & 63;
  const int wid  = tid >> 6;
  const int m0 = blockIdx.x * 128;
  const int which = blockIdx.y / 10;            // 0=Q 1=K 2=V
  const int n0 = (blockIdx.y % 10) * 128;
  const ushort* W = (which == 0) ? Wq : (which == 1) ? Wk : Wv;
  const int wr = (wid >> 1) * 64;
  const int wc = (wid & 1) * 64;

  f32x4 acc[4][4] = {};
  const int soff = wid * 4096 + lane * 16;

  for (int kk = 0; kk < K_; kk += 64) {
    __syncthreads();
#pragma unroll
    for (int i = 0; i < 4; ++i) {
      int off = soff + i * 1024;
      int row = off >> 7;
      int c8  = (off >> 4) & 7;
      int s8  = c8 ^ (row & 7);
      glds16(A + (size_t)(m0 + row) * K_ + kk + s8 * 8,
             (char*)Abuf + wid * 4096 + i * 1024);
      glds16(W + (size_t)(n0 + row) * K_ + kk + s8 * 8,
             (char*)Bbuf + wid * 4096 + i * 1024);
    }
    __syncthreads();
#pragma unroll
    for (int kt = 0; kt < 2; ++kt) {
      bf16x8 af[4], bfr[4];
#pragma unroll
      for (int mf = 0; mf < 4; ++mf) {
        int row  = wr + mf * 16 + (lane & 15);
        int byte = (row << 7) + kt * 64 + ((lane >> 4) << 4);
        af[mf] = *(const bf16x8*)((const char*)Abuf + (byte ^ ((row & 7) << 4)));
      }
#pragma unroll
      for (int nf = 0; nf < 4; ++nf) {
        int row  = wc + nf * 16 + (lane & 15);
        int byte = (row << 7) + kt * 64 + ((lane >> 4) << 4);
        bfr[nf] = *(const bf16x8*)((const char*)Bbuf + (byte ^ ((row & 7) << 4)));
      }
#pragma unroll
      for (int mf = 0; mf < 4; ++mf)
#pragma unroll
        for (int nf = 0; nf < 4; ++nf)
          acc[mf][nf] = __builtin_amdgcn_mfma_f32_16x16x32_bf16(
              af[mf], bfr[nf], acc[mf][nf], 0, 0, 0);
    }
  }

  // epilogue (block-uniform select)
#pragma unroll
  for (int mf = 0; mf < 4; ++mf) {
#pragma unroll
    for (int nf = 0; nf < 4; ++nf) {
      int mbase = m0 + wr + mf * 16 + ((lane >> 4) << 2);
      int n     = n0 + wc + nf * 16 + (lane & 15);
      int h = n >> 8, dd = n & 255;
      if (which == 0) {       // Q, pre-scaled by 1/sqrt(E)
#pragma unroll
        for (int r = 0; r < 4; ++r) {
          int m = mbase + r;
          Qo[((size_t)(((m >> 11) * H_ + h) * S_ + (m & 2047))) * D_ + dd] =
              f2bf(acc[mf][nf][r] * SCALE_);
        }
      } else if (which == 1) { // K
#pragma unroll
        for (int r = 0; r < 4; ++r) {
          int m = mbase + r;
          Ko[((size_t)(((m >> 11) * H_ + h) * S_ + (m & 2047))) * D_ + dd] =
              f2bf(acc[mf][nf][r]);
        }
      } else {                 // Vt [bh][d][s]
        size_t idx = ((size_t)((mbase >> 11) * H_ + h) * D_ + dd) * S_ + (mbase & 2047);
        ushort4 pk;
        pk.x = f2bf(acc[mf][nf][0]);
        pk.y = f2bf(acc[mf][nf][1]);
        pk.z = f2bf(acc[mf][nf][2]);
        pk.w = f2bf(acc[mf][nf][3]);
        *(ushort4*)(Vo + idx) = pk;
      }
    }
  }
}

// ---------------------------------------------------------------- output-proj GEMM (f32 + bias)
__global__ __launch_bounds__(256, 2)
void gemm_out(const ushort* __restrict__ A, const ushort* __restrict__ W,
              float* __restrict__ OF, const float* __restrict__ bias)
{
  __shared__ __align__(16) ushort Abuf[128 * 64];
  __shared__ __align__(16) ushort Bbuf[128 * 64];
  const int tid  = threadIdx.x;
  const int lane = tid & 63;
  const int wid  = tid >> 6;
  const int m0 = blockIdx.x * 128;
  const int n0 = blockIdx.y * 128;
  const int wr = (wid >> 1) * 64;
  const int wc = (wid & 1) * 64;

  f32x4 acc[4][4] = {};
  const int soff = wid * 4096 + lane * 16;

  for (int kk = 0; kk < K_; kk += 64) {
    __syncthreads();
#pragma unroll
    for (int i = 0; i < 4; ++i) {
      int off = soff + i * 1024;
      int row = off >> 7;
      int c8  = (off >> 4) & 7;
      int s8  = c8 ^ (row & 7);
      glds16(A + (size_t)(m0 + row) * K_ + kk + s8 * 8,
             (char*)Abuf + wid * 4096 + i * 1024);
      glds16(W + (size_t)(n0 + row) * K_ + kk + s8 * 8,
             (char*)Bbuf + wid * 4096 + i * 1024);
    }
    __syncthreads();
#pragma unroll
    for (int kt = 0; kt < 2; ++kt) {
      bf16x8 af[4], bfr[4];
#pragma unroll
      for (int mf = 0; mf < 4; ++mf) {
        int row  = wr + mf * 16 + (lane & 15);
        int byte = (row << 7) + kt * 64 + ((lane >> 4) << 4);
        af[mf] = *(const bf16x8*)((const char*)Abuf + (byte ^ ((row & 7) << 4)));
      }
#pragma unroll
      for (int nf = 0; nf < 4; ++nf) {
        int row  = wc + nf * 16 + (lane & 15);
        int byte = (row << 7) + kt * 64 + ((lane >> 4) << 4);
        bfr[nf] = *(const bf16x8*)((const char*)Bbuf + (byte ^ ((row & 7) << 4)));
      }
#pragma unroll
      for (int mf = 0; mf < 4; ++mf)
#pragma unroll
        for (int nf = 0; nf < 4; ++nf)
          acc[mf][nf] = __builtin_amdgcn_mfma_f32_16x16x32_bf16(
              af[mf], bfr[nf], acc[mf][nf], 0, 0, 0);
    }
  }

#pragma unroll
  for (int mf = 0; mf < 4; ++mf) {
#pragma unroll
    for (int nf = 0; nf < 4; ++nf) {
      int mbase = m0 + wr + mf * 16 + ((lane >> 4) << 2);
      int n     = n0 + wc + nf * 16 + (lane & 15);
      float bv = bias[n];
#pragma unroll
      for (int r = 0; r < 4; ++r)
        OF[(size_t)(mbase + r) * E_ + n] = acc[mf][nf][r] + bv;
    }
  }
}

// ---------------------------------------------------------------- flash attention (swapped QK^T)
// R5 structure (V double-buffered in LDS) + V quad-swizzle:
//   LDS[row][quad q] holds global V[row][q ^ ((row>>1)&3)]  (source pre-swizzled,
//   LDS dest linear per global_load_lds rules), read applies the same XOR.
//   Kills the 8-way bank conflict of linear [256][32] V reads (R7 isolated it at ~5.3M cycles).
// launch_bounds MUST stay (256,2): (256,4) spilled the O accumulator (R6: 990 MB scratch writes).
// Q(prescaled),K: [bh][s][d] bf16; Vt: [bh][d][s] bf16; AO: [b][s][e] bf16
__global__ __launch_bounds__(256, 2)
void flash_attn_kernel(const ushort* __restrict__ Q, const ushort* __restrict__ Kg,
                       const ushort* __restrict__ Vt, ushort* __restrict__ AO)
{
  __shared__ __align__(16) ushort Kbuf[2][32 * 256];   // 2 x 16 KB, swizzled
  __shared__ __align__(16) ushort Vbuf[2][256 * 32];   // 2 x 16 KB, quad-swizzled
  __shared__ __align__(16) char   Pbuf[4 * 16 * 80];   // per-wave P (16 x 32 bf16, pitch 80)

  const int lane = threadIdx.x & 63;
  const int wid  = threadIdx.x >> 6;
  const int l15  = lane & 15;
  const int l4   = lane >> 4;          // 0..3

  // XCD-clustered remap (640 % 8 == 0, bijective); big causal tiles first.
  const int id  = blockIdx.x;
  const int idp = (id & 7) * 80 + (id >> 3);
  const int bh  = idp >> 5;                    // 0..19
  const int tq  = 31 - (idp & 31);             // 0..31
  const int q0w = tq * 64 + wid * 16;          // this wave's 16 q-rows

  const ushort* Qb = Q  + (size_t)bh * S_ * D_;
  const ushort* Kb = Kg + (size_t)bh * S_ * D_;
  const ushort* Vb = Vt + (size_t)bh * D_ * S_;

  // Q fragments (B-operand): lane holds q=q0w+l15, d = kt*32 + l4*8 + j
  bf16x8 bq[8];
  {
    const ushort* qrow = Qb + (size_t)(q0w + l15) * D_ + l4 * 8;
#pragma unroll
    for (int kt = 0; kt < 8; ++kt) bq[kt] = *(const bf16x8*)(qrow + kt * 32);
  }

  f32x4 o[16] = {};
  float m_s = -1e30f, l_s = 0.f;       // stats for q = q0w + l15 (per-lane)

  char* Pw = Pbuf + wid * 1280;
  const int nt = 2 * tq + 2;

  // stage K [32][256] (row-swizzled src) + V [256][32] (quad-swizzled src)
#define STAGE_KV(bufi, kvbase)                                                \
  do {                                                                        \
    _Pragma("unroll")                                                         \
    for (int i_ = 0; i_ < 4; ++i_) {                                          \
      int off_ = wid * 4096 + i_ * 1024 + lane * 16;                          \
      int rK_  = off_ >> 9;                                                   \
      int s8_  = ((off_ >> 4) & 31) ^ (rK_ & 7);                              \
      glds16(Kb + (size_t)((kvbase) + rK_) * D_ + s8_ * 8,                    \
             (char*)Kbuf[bufi] + wid * 4096 + i_ * 1024);                     \
      int rV_  = off_ >> 6;                                                   \
      int qv_  = ((off_ >> 4) & 3) ^ ((rV_ >> 1) & 3);                        \
      glds16(Vb + (size_t)rV_ * S_ + (kvbase) + (qv_ << 3),                   \
             (char*)Vbuf[bufi] + wid * 4096 + i_ * 1024);                     \
    }                                                                         \
  } while (0)

  STAGE_KV(0, 0);
  __syncthreads();

  // V read swizzle: row = nf*16+l15 -> ((row>>1)&3) == ((l15>>1)&3), nf-independent
  const int vsw = (l4 ^ ((l15 >> 1) & 3)) << 4;

  int cur = 0;
  for (int t = 0; t < nt; ++t) {
    const int kv0 = t * 32;
    if (t + 1 < nt) STAGE_KV(cur ^ 1, kv0 + 32);   // issue-ahead (no wait)

    if (kv0 <= q0w + 15) {   // wave-uniform: skip fully-masked tiles
      // ---- S^T = K Q^T : sacc[h2] holds kv = kv0 + h2*16 + l4*4 + r, q = q0w + l15
      f32x4 sacc[2] = {};
      const char* kb = (const char*)Kbuf[cur];
      __builtin_amdgcn_s_setprio(1);
#pragma unroll
      for (int kt = 0; kt < 8; ++kt) {
#pragma unroll
        for (int h2 = 0; h2 < 2; ++h2) {
          int row  = h2 * 16 + l15;                       // kv-local row
          int byte = (row << 9) + kt * 64 + (l4 << 4);
          bf16x8 kf = *(const bf16x8*)(kb + (byte ^ ((row & 7) << 4)));
          sacc[h2] = __builtin_amdgcn_mfma_f32_16x16x32_bf16(kf, bq[kt], sacc[h2], 0, 0, 0);
        }
      }
      __builtin_amdgcn_s_setprio(0);

      // ---- online softmax (per-lane scalar stats for q = q0w + l15)
      const bool msk = (kv0 + 31 > q0w);
      float sv[2][4];
#pragma unroll
      for (int h2 = 0; h2 < 2; ++h2)
#pragma unroll
        for (int r = 0; r < 4; ++r) {
          float s = sacc[h2][r];                          // Q pre-scaled
          if (msk && (kv0 + h2 * 16 + l4 * 4 + r > q0w + l15)) s = -1e30f;
          sv[h2][r] = s;
        }
      float pm = sv[0][0];
#pragma unroll
      for (int h2 = 0; h2 < 2; ++h2)
#pragma unroll
        for (int r = 0; r < 4; ++r) pm = fmaxf(pm, sv[h2][r]);
      pm = fmaxf(pm, __shfl_xor(pm, 16, 64));
      pm = fmaxf(pm, __shfl_xor(pm, 32, 64));

      if (__any(pm > m_s + 8.f)) {     // rescale path
        float mn = fmaxf(m_s, pm);
        float alpha = __expf(m_s - mn);
        m_s = mn;
#pragma unroll
        for (int h2 = 0; h2 < 2; ++h2)
#pragma unroll
          for (int r = 0; r < 4; ++r) sv[h2][r] = __expf(sv[h2][r] - m_s);
        float rs = 0.f;
#pragma unroll
        for (int h2 = 0; h2 < 2; ++h2)
#pragma unroll
          for (int r = 0; r < 4; ++r) rs += sv[h2][r];
        rs += __shfl_xor(rs, 16, 64);
        rs += __shfl_xor(rs, 32, 64);
        l_s = l_s * alpha + rs;
        // redistribute alpha from q=l15 lanes to q=l4*4+r accumulator rows
        float al[4];
#pragma unroll
        for (int r = 0; r < 4; ++r)
          al[r] = __shfl(alpha, (lane & 48) + ((lane & 48) >> 2) + r, 64);
#pragma unroll
        for (int nf = 0; nf < 16; ++nf)
#pragma unroll
          for (int r = 0; r < 4; ++r) o[nf][r] *= al[r];
      } else {                         // defer-max (T13): no rescale
#pragma unroll
        for (int h2 = 0; h2 < 2; ++h2)
#pragma unroll
          for (int r = 0; r < 4; ++r) sv[h2][r] = __expf(sv[h2][r] - m_s);
        float rs = 0.f;
#pragma unroll
        for (int h2 = 0; h2 < 2; ++h2)
#pragma unroll
          for (int r = 0; r < 4; ++r) rs += sv[h2][r];
        rs += __shfl_xor(rs, 16, 64);
        rs += __shfl_xor(rs, 32, 64);
        l_s += rs;
      }

      // ---- P to wave-private LDS: row q=l15, cols kv = h2*16 + l4*4 + {0..3}
      ushort4 w0, w1;
      w0.x = f2bf(sv[0][0]); w0.y = f2bf(sv[0][1]); w0.z = f2bf(sv[0][2]); w0.w = f2bf(sv[0][3]);
      w1.x = f2bf(sv[1][0]); w1.y = f2bf(sv[1][1]); w1.z = f2bf(sv[1][2]); w1.w = f2bf(sv[1][3]);
      *(ushort4*)(Pw + l15 * 80 + l4 * 8)      = w0;
      *(ushort4*)(Pw + l15 * 80 + 32 + l4 * 8) = w1;
      bf16x8 pa = *(const bf16x8*)(Pw + l15 * 80 + l4 * 16);  // A-frag: row l15, k=l4*8..+7

      // ---- O += P V  (C[q][d]: q = l4*4+r, d = nf*16+l15); V from LDS, quad-swizzled
      const char* vb = (const char*)Vbuf[cur];
      __builtin_amdgcn_s_setprio(1);
#pragma unroll
      for (int nf = 0; nf < 16; ++nf) {
        bf16x8 bv = *(const bf16x8*)(vb + ((nf * 16 + l15) << 6) + vsw);
        o[nf] = __builtin_amdgcn_mfma_f32_16x16x32_bf16(pa, bv, o[nf], 0, 0, 0);
      }
      __builtin_amdgcn_s_setprio(0);
    }

    __syncthreads();   // single per-iter drain
    cur ^= 1;
  }
#undef STAGE_KV

  // ---- epilogue: redistribute 1/l (q=l15 -> q=l4*4+r), write bf16
  float linv = 1.0f / l_s;
  float inv[4];
#pragma unroll
  for (int r = 0; r < 4; ++r)
    inv[r] = __shfl(linv, (lane & 48) + ((lane & 48) >> 2) + r, 64);
  int b = bh / H_, h = bh % H_;
  const int dd0 = h * D_;
#pragma unroll
  for (int nf = 0; nf < 16; ++nf) {
    int dd = dd0 + nf * 16 + l15;
#pragma unroll
    for (int r = 0; r < 4; ++r) {
      int s = q0w + l4 * 4 + r;
      AO[(size_t)(b * S_ + s) * E_ + dd] = f2bf(o[nf][r] * inv[r]);
    }
  }
}

// ---------------------------------------------------------------- launch
extern "C" void kernel_launch(void* const* d_in, const int* in_sizes, int n_in,
                              void* d_out, int out_size, void* d_ws, size_t ws_size,
                              hipStream_t stream) {
  const float* x  = (const float*)d_in[0];
  const float* Wq = (const float*)d_in[1];
  const float* Wk = (const float*)d_in[2];
  const float* Wv = (const float*)d_in[3];
  const float* Wu = (const float*)d_in[4];
  const float* bu = (const float*)d_in[5];

  char* ws = (char*)d_ws;
  ushort* xbf = (ushort*)(ws + 0);          // 8192x1280 bf16
  ushort* Wqb = (ushort*)(ws + 20971520);
  ushort* Wkb = (ushort*)(ws + 24248320);
  ushort* Wvb = (ushort*)(ws + 27525120);
  ushort* Wub = (ushort*)(ws + 30801920);
  ushort* Qw  = (ushort*)(ws + 34078720);   // [20][2048][256] (pre-scaled)
  ushort* Kw  = (ushort*)(ws + 55050240);   // [20][2048][256]
  ushort* Vtw = (ushort*)(ws + 76021760);   // [20][256][2048]
  ushort* AOw = (ushort*)(ws + 96993280);   // [4][2048][1280]

  cvt5_kernel<<<dim3(1024, 5), 256, 0, stream>>>(
      (const float4*)x, (const float4*)Wq, (const float4*)Wk,
      (const float4*)Wv, (const float4*)Wu,
      (ushort4*)xbf, (ushort4*)Wqb, (ushort4*)Wkb, (ushort4*)Wvb, (ushort4*)Wub,
      M_ * K_ / 4, E_ * E_ / 4);

  gemm_qkv<<<dim3(M_ / 128, 30), 256, 0, stream>>>(xbf, Wqb, Wkb, Wvb, Qw, Kw, Vtw);

  flash_attn_kernel<<<640, 256, 0, stream>>>(Qw, Kw, Vtw, AOw);

  gemm_out<<<dim3(M_ / 128, E_ / 128), 256, 0, stream>>>(AOw, Wub, (float*)d_out, bu);
}